// Round 15
// baseline (426.557 us; speedup 1.0000x reference)
//
#include <hip/hip_runtime.h>

#define NLVL 16
#define NDENSE 8            // levels 0..7 -> blocked dense (2x2x1 fp16 quads)
#define BDENSE_CAP 1100000  // max blocks (16B each); levels 0..7 need ~1.06M

typedef float f32x2 __attribute__((ext_vector_type(2)));
typedef float f32x4 __attribute__((ext_vector_type(4)));
typedef _Float16 f16x2 __attribute__((ext_vector_type(2)));
typedef unsigned u32x2 __attribute__((ext_vector_type(2)));

__device__ __forceinline__ unsigned hash3(unsigned x, unsigned y, unsigned z) {
    return x ^ (y * 2654435761u) ^ (z * 805459861u);
}

// blocks per level: R*R*(R+1); block(cx,cy,z) holds corners (cx..cx+1, cy..cy+1, z)
// linear block id = z*R*R + cy*R + cx
__device__ __forceinline__ unsigned bdense_total(const int* __restrict__ resolutions,
                                                 unsigned bdoff[NDENSE]) {
    unsigned acc = 0;
    for (int ll = 0; ll < NDENSE; ++ll) {
        unsigned R = (unsigned)resolutions[ll];
        bdoff[ll] = acc;
        acc += R * R * (R + 1u);
    }
    return acc;
}

// ---- pre-pass A: f32 table -> fp16 table (all levels, hashed layout) ----
__global__ __launch_bounds__(256) void convert_fp16_kernel(
    const float* __restrict__ emb,
    _Float16*    __restrict__ htab,
    int n_entries)
{
    int i = blockIdx.x * 256 + (int)threadIdx.x;
    if (i >= n_entries) return;
    f32x2 v = reinterpret_cast<const f32x2*>(emb)[i];
    f16x2 h;
    h.x = (_Float16)v.x;
    h.y = (_Float16)v.y;
    reinterpret_cast<f16x2*>(htab)[i] = h;
}

// ---- pre-pass B: gather 2x2x1 quads FROM HTAB (bitwise-identical words) ----
// bdense[tid*4 + (j*2+i)] = htab_word(level l, hash(cx+i, cy+j, z))
__global__ __launch_bounds__(256) void bdensify_kernel(
    const unsigned* __restrict__ htab32,
    const int*      __restrict__ offsets,
    const int*      __restrict__ resolutions,
    unsigned*       __restrict__ bdense)
{
    unsigned bdoff[NDENSE];
    unsigned total = bdense_total(resolutions, bdoff);
    if (total > BDENSE_CAP) total = BDENSE_CAP;
    unsigned tid = blockIdx.x * 256u + threadIdx.x;
    if (tid >= total) return;
    int l = 0;
    while (l < NDENSE - 1 && tid >= bdoff[l + 1]) ++l;
    unsigned idx = tid - bdoff[l];
    unsigned R = (unsigned)resolutions[l];
    unsigned cx = idx % R;
    unsigned t  = idx / R;
    unsigned cy = t % R;
    unsigned z  = t / R;
    unsigned off  = (unsigned)offsets[l];
    unsigned size = (unsigned)offsets[l + 1] - off;
    unsigned mask = size - 1u;
    bool pow2 = (size & mask) == 0u;
    const unsigned* src = htab32 + off;

    unsigned q[4];
    {
        unsigned h = hash3(cx,      cy,      z);
        q[0] = src[pow2 ? (h & mask) : (h % size)];
    }
    {
        unsigned h = hash3(cx + 1u, cy,      z);
        q[1] = src[pow2 ? (h & mask) : (h % size)];
    }
    {
        unsigned h = hash3(cx,      cy + 1u, z);
        q[2] = src[pow2 ? (h & mask) : (h % size)];
    }
    {
        unsigned h = hash3(cx + 1u, cy + 1u, z);
        q[3] = src[pow2 ? (h & mask) : (h % size)];
    }
    __builtin_memcpy(bdense + (size_t)tid * 4u, q, 16);
}

// ---- main: one block = one level x 256 points ----
// XCD = blockIdx.x % 8. g = blockIdx.x & 15:
//   g 0..7  -> PINNED fine level 8+g on XCD g (fp16 table 2 MiB, L2-resident)
//   g 8..15 -> SPREAD {levels 0..7, all blocked-dense} rotating every 64 chunks.
// Fine hashed: fp16 x-pair merge (avg 6 lane-req/point).
// Blocked-dense levels 0..7: 2 x 16B memcpy loads/point (quad at z, quad z+1).
// Stores: fp16 scratch[l*B+p], coalesced; transpose makes f32 out[p][l].
__global__ __launch_bounds__(256) void encode_kernel(
    const float* __restrict__ xyz,
    const float* __restrict__ emb,
    const _Float16* __restrict__ htab,
    const int*   __restrict__ offsets,
    const int*   __restrict__ resolutions,
    const float* __restrict__ min_xyz,
    const float* __restrict__ max_xyz,
    const unsigned* __restrict__ bdense,
    float*       __restrict__ scratch,
    float*       __restrict__ out,
    int B, int use_bdense, int use_scratch, int use_fp16)
{
    const int g = blockIdx.x & 15;
    const int chunk = blockIdx.x >> 4;
    const int l = (g < 8) ? (8 + g) : (((g - 8) + (chunk >> 6)) & 7);
    const int p = chunk * 256 + (int)threadIdx.x;
    if (p >= B) return;

    const float res = (float)resolutions[l];
    const unsigned off  = (unsigned)offsets[l];
    const unsigned size = (unsigned)offsets[l + 1] - off;
    const unsigned mask = size - 1u;
    const bool pow2 = (size & mask) == 0u;
    const float mn0 = min_xyz[0], mn1 = min_xyz[1], mn2 = min_xyz[2];
    const float mx0 = max_xyz[0], mx1 = max_xyz[1], mx2 = max_xyz[2];

    const float x = xyz[p * 3 + 0];
    const float y = xyz[p * 3 + 1];
    const float z = xyz[p * 3 + 2];
    // bit-exact fp32 chain (matches reference op order)
    const float ux = (x - mn0) / (mx0 - mn0);
    const float uy = (y - mn1) / (mx1 - mn1);
    const float uz = (z - mn2) / (mx2 - mn2);
    const bool valid = (ux >= 0.0f) & (ux <= 1.0f) &
                       (uy >= 0.0f) & (uy <= 1.0f) &
                       (uz >= 0.0f) & (uz <= 1.0f);

    const float rm1 = res - 1.0f;
    const float px = ux * res, py = uy * res, pz = uz * res;
    const float p0x = fminf(fmaxf(floorf(px), 0.0f), rm1);
    const float p0y = fminf(fmaxf(floorf(py), 0.0f), rm1);
    const float p0z = fminf(fmaxf(floorf(pz), 0.0f), rm1);
    const float fx = px - p0x, fy = py - p0y, fz = pz - p0z;
    const float gx = 1.0f - fx, gy = 1.0f - fy, gz = 1.0f - fz;
    const unsigned cx0 = (unsigned)p0x;
    const unsigned cy0 = (unsigned)p0y;
    const unsigned cz0 = (unsigned)p0z;

    const unsigned P1 = 2654435761u;
    const unsigned P2 = 805459861u;

    float o0 = 0.0f, o1 = 0.0f;

    bool bdense_ok = false;
    unsigned bdoff[NDENSE];
    if (use_bdense && l < NDENSE) {
        unsigned total = bdense_total(resolutions, bdoff);
        bdense_ok = (total <= BDENSE_CAP);
    }

    if (bdense_ok) {
        // blocked dense: 2 x 16B loads cover all 8 corners at any parity
        const unsigned R = (unsigned)resolutions[l];
        const unsigned base = bdoff[l] + (cz0 * R + cy0) * R + cx0;
        unsigned q0[4], q1[4];
        __builtin_memcpy(q0, bdense + (size_t)base * 4u, 16);
        __builtin_memcpy(q1, bdense + (size_t)(base + R * R) * 4u, 16);
        f16x2 e0 = __builtin_bit_cast(f16x2, q0[0]);   // (cx0  ,cy0  ,cz0)
        f16x2 e1 = __builtin_bit_cast(f16x2, q0[1]);   // (cx0+1,cy0  ,cz0)
        f16x2 e2 = __builtin_bit_cast(f16x2, q0[2]);   // (cx0  ,cy0+1,cz0)
        f16x2 e3 = __builtin_bit_cast(f16x2, q0[3]);   // (cx0+1,cy0+1,cz0)
        f16x2 e4 = __builtin_bit_cast(f16x2, q1[0]);   // z+1 ...
        f16x2 e5 = __builtin_bit_cast(f16x2, q1[1]);
        f16x2 e6 = __builtin_bit_cast(f16x2, q1[2]);
        f16x2 e7 = __builtin_bit_cast(f16x2, q1[3]);
        o0 += (gx * gy * gz) * (float)e0.x;  o1 += (gx * gy * gz) * (float)e0.y;  // c=0
        o0 += (fx * gy * gz) * (float)e1.x;  o1 += (fx * gy * gz) * (float)e1.y;  // c=1
        o0 += (gx * fy * gz) * (float)e2.x;  o1 += (gx * fy * gz) * (float)e2.y;  // c=2
        o0 += (fx * fy * gz) * (float)e3.x;  o1 += (fx * fy * gz) * (float)e3.y;  // c=3
        o0 += (gx * gy * fz) * (float)e4.x;  o1 += (gx * gy * fz) * (float)e4.y;  // c=4
        o0 += (fx * gy * fz) * (float)e5.x;  o1 += (fx * gy * fz) * (float)e5.y;  // c=5
        o0 += (gx * fy * fz) * (float)e6.x;  o1 += (gx * fy * fz) * (float)e6.y;  // c=6
        o0 += (fx * fy * fz) * (float)e7.x;  o1 += (fx * fy * fz) * (float)e7.y;  // c=7
    } else if (use_fp16 && pow2) {
        // hashed level via fp16 table with x-pair merge
        const unsigned* lvl32 = reinterpret_cast<const unsigned*>(htab) + off;
        const u32x2*    lvlp  = reinterpret_cast<const u32x2*>(lvl32);
        unsigned m4[4], h0a[4];
        u32x2 pr[4];
#pragma unroll
        for (int pi = 0; pi < 4; ++pi) {
            unsigned by = (unsigned)(pi & 1);
            unsigned bz = (unsigned)(pi >> 1);
            unsigned m = ((cy0 + by) * P1) ^ ((cz0 + bz) * P2);
            unsigned h0 = (cx0 ^ m) & mask;
            m4[pi] = m; h0a[pi] = h0;
            pr[pi] = lvlp[h0 >> 1];          // aligned 8B pair {h0&~1, h0|1}
        }
        unsigned e0b[4], e1b[4];
        if ((cx0 & 1u) == 0u) {
#pragma unroll
            for (int pi = 0; pi < 4; ++pi) {
                bool hi = (h0a[pi] & 1u) != 0u;
                e0b[pi] = hi ? pr[pi].y : pr[pi].x;
                e1b[pi] = hi ? pr[pi].x : pr[pi].y;
            }
        } else {
#pragma unroll
            for (int pi = 0; pi < 4; ++pi) {
                unsigned h1 = ((cx0 + 1u) ^ m4[pi]) & mask;
                e1b[pi] = lvl32[h1];
                e0b[pi] = (h0a[pi] & 1u) ? pr[pi].y : pr[pi].x;
            }
        }
#pragma unroll
        for (int pi = 0; pi < 4; ++pi) {
            unsigned by = (unsigned)(pi & 1);
            unsigned bz = (unsigned)(pi >> 1);
            float wy = by ? fy : gy;
            float wz = bz ? fz : gz;
            float wyz = wy * wz;
            f16x2 e0 = __builtin_bit_cast(f16x2, e0b[pi]);
            f16x2 e1 = __builtin_bit_cast(f16x2, e1b[pi]);
            float w0 = gx * wyz;
            float w1 = fx * wyz;
            o0 += w0 * (float)e0.x;  o1 += w0 * (float)e0.y;   // c = 2by+4bz
            o0 += w1 * (float)e1.x;  o1 += w1 * (float)e1.y;   // c = 2by+4bz+1
        }
    } else {
        const f32x2* lvl = reinterpret_cast<const f32x2*>(emb) + off;
#pragma unroll
        for (int c = 0; c < 8; ++c) {
            unsigned bx = (unsigned)(c & 1);
            unsigned by = (unsigned)((c >> 1) & 1);
            unsigned bz = (unsigned)((c >> 2) & 1);
            unsigned h = hash3(cx0 + bx, cy0 + by, cz0 + bz);
            unsigned hm = pow2 ? (h & mask) : (h % size);
            f32x2 e = lvl[hm];
            float w = (bx ? fx : gx) * (by ? fy : gy);
            w = w * (bz ? fz : gz);
            o0 += w * e.x;
            o1 += w * e.y;
        }
    }

    if (!valid) { o0 = 0.0f; o1 = 0.0f; }
    if (use_scratch) {
        f16x2 h; h.x = (_Float16)o0; h.y = (_Float16)o1;
        unsigned hb = __builtin_bit_cast(unsigned, h);
        unsigned* op = reinterpret_cast<unsigned*>(scratch) + (size_t)l * B + p;
        __builtin_nontemporal_store(hb, op);
    } else {
        f32x2 r; r.x = o0; r.y = o1;
        f32x2* op = reinterpret_cast<f32x2*>(out + (size_t)p * (NLVL * 2) + l * 2);
        __builtin_nontemporal_store(r, op);
    }
}

// ---- transpose scratch(fp16)[l][p] -> out(f32)[p][l] via LDS tile ----
__global__ __launch_bounds__(256) void transpose_kernel(
    const float* __restrict__ scratch,
    float*       __restrict__ out,
    int B)
{
    __shared__ float tile[64][33];
    const int p0 = blockIdx.x * 64;
    const int tid = (int)threadIdx.x;

    const unsigned* src = reinterpret_cast<const unsigned*>(scratch);
#pragma unroll
    for (int k = 0; k < 4; ++k) {
        int it = tid + k * 256;
        int l  = it >> 6;
        int pi = it & 63;
        int p  = p0 + pi;
        unsigned vb = (p < B) ? src[(size_t)l * B + p] : 0u;
        f16x2 v = __builtin_bit_cast(f16x2, vb);
        tile[pi][2 * l]     = (float)v.x;
        tile[pi][2 * l + 1] = (float)v.y;
    }
    __syncthreads();

    const int pl = tid >> 2;
    const int q  = tid & 3;
    const int p  = p0 + pl;
    if (p >= B) return;
    float vals[8];
#pragma unroll
    for (int j = 0; j < 8; ++j) vals[j] = tile[pl][q * 8 + j];
    f32x4 lo, hi;
    lo.x = vals[0]; lo.y = vals[1]; lo.z = vals[2]; lo.w = vals[3];
    hi.x = vals[4]; hi.y = vals[5]; hi.z = vals[6]; hi.w = vals[7];
    f32x4* dst = reinterpret_cast<f32x4*>(out + (size_t)p * 32 + q * 8);
    __builtin_nontemporal_store(lo, dst);
    __builtin_nontemporal_store(hi, dst + 1);
}

extern "C" void kernel_launch(void* const* d_in, const int* in_sizes, int n_in,
                              void* d_out, int out_size, void* d_ws, size_t ws_size,
                              hipStream_t stream) {
    const float* xyz        = (const float*)d_in[0];
    const float* embeddings = (const float*)d_in[1];
    const int*   offsets    = (const int*)d_in[2];
    const int*   resolutions= (const int*)d_in[3];
    const float* min_xyz    = (const float*)d_in[4];
    const float* max_xyz    = (const float*)d_in[5];
    float* out = (float*)d_out;

    int B = in_sizes[0] / 3;
    int n_entries = in_sizes[1] / 2;                       // total table entries (F=2)

    size_t scratch_bytes = (size_t)B * NLVL * 4;           // f16x2 per (l,p)
    size_t htab_bytes    = (size_t)n_entries * 4;          // f16x2 per entry
    size_t bdense_bytes  = (size_t)BDENSE_CAP * 16;        // 16B quads

    int use_scratch = (ws_size >= scratch_bytes) ? 1 : 0;
    size_t htab_off = use_scratch ? scratch_bytes : 0;
    int use_fp16 = (ws_size >= htab_off + htab_bytes) ? 1 : 0;
    size_t bdense_off = htab_off + (use_fp16 ? htab_bytes : 0);
    int use_bdense = (use_fp16 && ws_size >= bdense_off + bdense_bytes) ? 1 : 0;

    float*    scratch = (float*)d_ws;
    _Float16* htab    = (_Float16*)((char*)d_ws + htab_off);
    unsigned* bdense  = (unsigned*)((char*)d_ws + bdense_off);

    if (use_fp16) {
        int cgrid = (n_entries + 255) / 256;
        convert_fp16_kernel<<<cgrid, 256, 0, stream>>>(embeddings, htab, n_entries);
    }
    if (use_bdense) {
        int pgrid = (BDENSE_CAP + 255) / 256;
        bdensify_kernel<<<pgrid, 256, 0, stream>>>(
            (const unsigned*)htab, offsets, resolutions, bdense);
    }
    int nchunks = (B + 255) / 256;
    int grid = nchunks * NLVL;
    encode_kernel<<<grid, 256, 0, stream>>>(
        xyz, embeddings, htab, offsets, resolutions, min_xyz, max_xyz,
        bdense, scratch, out, B, use_bdense, use_scratch, use_fp16);
    if (use_scratch) {
        int tgrid = (B + 63) / 64;
        transpose_kernel<<<tgrid, 256, 0, stream>>>(scratch, out, B);
    }
}

// Round 16
// 401.340 us; speedup vs baseline: 1.0628x; 1.0628x over previous
//
#include <hip/hip_runtime.h>

#define NLVL 16
#define NDENSE 7            // levels 0..6 -> blocked dense (2x2x1 fp16 quads)
#define BDENSE_CAP 600000   // max blocks (16B each) the pre-pass covers
#define PPT 4               // points per thread (gather ILP)

typedef float f32x2 __attribute__((ext_vector_type(2)));
typedef float f32x4 __attribute__((ext_vector_type(4)));
typedef _Float16 f16x2 __attribute__((ext_vector_type(2)));
typedef unsigned u32x2 __attribute__((ext_vector_type(2)));
typedef unsigned u32x4 __attribute__((ext_vector_type(4)));

__device__ __forceinline__ unsigned hash3(unsigned x, unsigned y, unsigned z) {
    return x ^ (y * 2654435761u) ^ (z * 805459861u);
}

// blocks per level: R*R*(R+1); block(cx,cy,z) holds corners (cx..cx+1, cy..cy+1, z)
__device__ __forceinline__ unsigned bdense_total(const int* __restrict__ resolutions,
                                                 unsigned bdoff[NDENSE]) {
    unsigned acc = 0;
    for (int ll = 0; ll < NDENSE; ++ll) {
        unsigned R = (unsigned)resolutions[ll];
        bdoff[ll] = acc;
        acc += R * R * (R + 1u);
    }
    return acc;
}

// ---- pre-pass A: f32 table -> fp16 table (all levels, hashed layout) ----
__global__ __launch_bounds__(256) void convert_fp16_kernel(
    const float* __restrict__ emb,
    _Float16*    __restrict__ htab,
    int n_entries)
{
    int i = blockIdx.x * 256 + (int)threadIdx.x;
    if (i >= n_entries) return;
    f32x2 v = reinterpret_cast<const f32x2*>(emb)[i];
    f16x2 h;
    h.x = (_Float16)v.x;
    h.y = (_Float16)v.y;
    reinterpret_cast<f16x2*>(htab)[i] = h;
}

// ---- pre-pass B: gather 2x2x1 quads FROM HTAB (bitwise-identical words) ----
__global__ __launch_bounds__(256) void bdensify_kernel(
    const unsigned* __restrict__ htab32,
    const int*      __restrict__ offsets,
    const int*      __restrict__ resolutions,
    unsigned*       __restrict__ bdense)
{
    unsigned bdoff[NDENSE];
    unsigned total = bdense_total(resolutions, bdoff);
    if (total > BDENSE_CAP) total = BDENSE_CAP;
    unsigned tid = blockIdx.x * 256u + threadIdx.x;
    if (tid >= total) return;
    int l = 0;
    while (l < NDENSE - 1 && tid >= bdoff[l + 1]) ++l;
    unsigned idx = tid - bdoff[l];
    unsigned R = (unsigned)resolutions[l];
    unsigned cx = idx % R;
    unsigned t  = idx / R;
    unsigned cy = t % R;
    unsigned z  = t / R;
    unsigned off  = (unsigned)offsets[l];
    unsigned size = (unsigned)offsets[l + 1] - off;
    unsigned mask = size - 1u;
    bool pow2 = (size & mask) == 0u;
    const unsigned* src = htab32 + off;

    unsigned q[4];
    {
        unsigned h = hash3(cx,      cy,      z);
        q[0] = src[pow2 ? (h & mask) : (h % size)];
    }
    {
        unsigned h = hash3(cx + 1u, cy,      z);
        q[1] = src[pow2 ? (h & mask) : (h % size)];
    }
    {
        unsigned h = hash3(cx,      cy + 1u, z);
        q[2] = src[pow2 ? (h & mask) : (h % size)];
    }
    {
        unsigned h = hash3(cx + 1u, cy + 1u, z);
        q[3] = src[pow2 ? (h & mask) : (h % size)];
    }
    __builtin_memcpy(bdense + (size_t)tid * 4u, q, 16);
}

// ---- main: one block = one level x 1024 points (4 pts/thread) ----
// XCD = blockIdx.x % 8. g = blockIdx.x & 15:
//   g 0..7  -> PINNED fine level 8+g on XCD g (fp16 table 2 MiB, L2-resident)
//   g 8..15 -> SPREAD {level 7 hashed, blocked-dense 0..6} rotating /64 chunks.
// Fine hashed: fp16 x-pair merge; ALL 16 pair loads (4pts x 4) issued before
// any consumption -> 4x deeper vmem pipeline (latency hiding).
// Stores: one 16B u32x4 nontemporal per thread to fp16 scratch (coalesced).
__global__ __launch_bounds__(256) void encode_kernel(
    const float* __restrict__ xyz,
    const float* __restrict__ emb,
    const _Float16* __restrict__ htab,
    const int*   __restrict__ offsets,
    const int*   __restrict__ resolutions,
    const float* __restrict__ min_xyz,
    const float* __restrict__ max_xyz,
    const unsigned* __restrict__ bdense,
    float*       __restrict__ scratch,
    float*       __restrict__ out,
    int B, int use_bdense, int use_scratch, int use_fp16)
{
    const int g = blockIdx.x & 15;
    const int chunk = blockIdx.x >> 4;
    const int l = (g < 8) ? (8 + g) : (((g - 8) + (chunk >> 6)) & 7);
    const int p0 = chunk * (256 * PPT) + (int)threadIdx.x * PPT;
    if (p0 >= B) return;

    const float res = (float)resolutions[l];
    const unsigned off  = (unsigned)offsets[l];
    const unsigned size = (unsigned)offsets[l + 1] - off;
    const unsigned mask = size - 1u;
    const bool pow2 = (size & mask) == 0u;
    const float mn0 = min_xyz[0], mn1 = min_xyz[1], mn2 = min_xyz[2];
    const float mx0 = max_xyz[0], mx1 = max_xyz[1], mx2 = max_xyz[2];

    const unsigned P1 = 2654435761u;
    const unsigned P2 = 805459861u;

    // ---- load PPT points' xyz (48B = 3 x 16B, aligned since p0 % 4 == 0) ----
    float X[PPT], Y[PPT], Z[PPT];
    if (p0 + PPT <= B) {
        f32x4 v0, v1, v2;
        __builtin_memcpy(&v0, xyz + (size_t)p0 * 3,      16);
        __builtin_memcpy(&v1, xyz + (size_t)p0 * 3 + 4,  16);
        __builtin_memcpy(&v2, xyz + (size_t)p0 * 3 + 8,  16);
        X[0] = v0.x; Y[0] = v0.y; Z[0] = v0.z;
        X[1] = v0.w; Y[1] = v1.x; Z[1] = v1.y;
        X[2] = v1.z; Y[2] = v1.w; Z[2] = v2.x;
        X[3] = v2.y; Y[3] = v2.z; Z[3] = v2.w;
    } else {
#pragma unroll
        for (int i = 0; i < PPT; ++i) {
            int p = p0 + i; if (p > B - 1) p = B - 1;
            X[i] = xyz[p * 3 + 0]; Y[i] = xyz[p * 3 + 1]; Z[i] = xyz[p * 3 + 2];
        }
    }

    // ---- per-point setup: bit-exact fp32 chain (matches reference) ----
    float fxa[PPT], fya[PPT], fza[PPT], qxa[PPT], qya[PPT], qza[PPT];
    unsigned cxa[PPT], cya[PPT], cza[PPT];
    bool valid[PPT];
#pragma unroll
    for (int i = 0; i < PPT; ++i) {
        float ux = (X[i] - mn0) / (mx0 - mn0);
        float uy = (Y[i] - mn1) / (mx1 - mn1);
        float uz = (Z[i] - mn2) / (mx2 - mn2);
        valid[i] = (ux >= 0.0f) & (ux <= 1.0f) &
                   (uy >= 0.0f) & (uy <= 1.0f) &
                   (uz >= 0.0f) & (uz <= 1.0f);
        float rm1 = res - 1.0f;
        float px = ux * res, py = uy * res, pz = uz * res;
        float p0x = fminf(fmaxf(floorf(px), 0.0f), rm1);
        float p0y = fminf(fmaxf(floorf(py), 0.0f), rm1);
        float p0z = fminf(fmaxf(floorf(pz), 0.0f), rm1);
        fxa[i] = px - p0x; fya[i] = py - p0y; fza[i] = pz - p0z;
        qxa[i] = 1.0f - fxa[i]; qya[i] = 1.0f - fya[i]; qza[i] = 1.0f - fza[i];
        cxa[i] = (unsigned)p0x; cya[i] = (unsigned)p0y; cza[i] = (unsigned)p0z;
    }

    float o0a[PPT], o1a[PPT];
#pragma unroll
    for (int i = 0; i < PPT; ++i) { o0a[i] = 0.0f; o1a[i] = 0.0f; }

    bool bdense_ok = false;
    unsigned bdoff[NDENSE];
    if (use_bdense && l < NDENSE) {
        unsigned total = bdense_total(resolutions, bdoff);
        bdense_ok = (total <= BDENSE_CAP);
    }

    if (bdense_ok) {
        const unsigned R = (unsigned)resolutions[l];
        unsigned base[PPT];
#pragma unroll
        for (int i = 0; i < PPT; ++i)
            base[i] = bdoff[l] + (cza[i] * R + cya[i]) * R + cxa[i];
        // issue all 2*PPT 16B loads before consuming
        unsigned q0[PPT][4], q1[PPT][4];
#pragma unroll
        for (int i = 0; i < PPT; ++i)
            __builtin_memcpy(q0[i], bdense + (size_t)base[i] * 4u, 16);
#pragma unroll
        for (int i = 0; i < PPT; ++i)
            __builtin_memcpy(q1[i], bdense + (size_t)(base[i] + R * R) * 4u, 16);
#pragma unroll
        for (int i = 0; i < PPT; ++i) {
            float fx = fxa[i], fy = fya[i], fz = fza[i];
            float gx = qxa[i], gy = qya[i], gz = qza[i];
            f16x2 e0 = __builtin_bit_cast(f16x2, q0[i][0]);
            f16x2 e1 = __builtin_bit_cast(f16x2, q0[i][1]);
            f16x2 e2 = __builtin_bit_cast(f16x2, q0[i][2]);
            f16x2 e3 = __builtin_bit_cast(f16x2, q0[i][3]);
            f16x2 e4 = __builtin_bit_cast(f16x2, q1[i][0]);
            f16x2 e5 = __builtin_bit_cast(f16x2, q1[i][1]);
            f16x2 e6 = __builtin_bit_cast(f16x2, q1[i][2]);
            f16x2 e7 = __builtin_bit_cast(f16x2, q1[i][3]);
            float o0 = 0.0f, o1 = 0.0f;
            o0 += (gx * gy * gz) * (float)e0.x;  o1 += (gx * gy * gz) * (float)e0.y;
            o0 += (fx * gy * gz) * (float)e1.x;  o1 += (fx * gy * gz) * (float)e1.y;
            o0 += (gx * fy * gz) * (float)e2.x;  o1 += (gx * fy * gz) * (float)e2.y;
            o0 += (fx * fy * gz) * (float)e3.x;  o1 += (fx * fy * gz) * (float)e3.y;
            o0 += (gx * gy * fz) * (float)e4.x;  o1 += (gx * gy * fz) * (float)e4.y;
            o0 += (fx * gy * fz) * (float)e5.x;  o1 += (fx * gy * fz) * (float)e5.y;
            o0 += (gx * fy * fz) * (float)e6.x;  o1 += (gx * fy * fz) * (float)e6.y;
            o0 += (fx * fy * fz) * (float)e7.x;  o1 += (fx * fy * fz) * (float)e7.y;
            o0a[i] = o0; o1a[i] = o1;
        }
    } else if (use_fp16 && pow2) {
        const unsigned* lvl32 = reinterpret_cast<const unsigned*>(htab) + off;
        const u32x2*    lvlp  = reinterpret_cast<const u32x2*>(lvl32);
        // phase 1: issue ALL pair loads (PPT x 4) -> deep pipeline
        u32x2 pr[PPT][4];
#pragma unroll
        for (int i = 0; i < PPT; ++i) {
#pragma unroll
            for (int pi = 0; pi < 4; ++pi) {
                unsigned m = ((cya[i] + (unsigned)(pi & 1)) * P1) ^
                             ((cza[i] + (unsigned)(pi >> 1)) * P2);
                unsigned h0 = (cxa[i] ^ m) & mask;
                pr[i][pi] = lvlp[h0 >> 1];
            }
        }
        // phase 2: consume (recompute m/h0 in VALU; odd-x lanes load e1)
#pragma unroll
        for (int i = 0; i < PPT; ++i) {
            float fx = fxa[i], fy = fya[i], fz = fza[i];
            float gx = qxa[i], gy = qya[i], gz = qza[i];
            bool odd = (cxa[i] & 1u) != 0u;
            float o0 = 0.0f, o1 = 0.0f;
#pragma unroll
            for (int pi = 0; pi < 4; ++pi) {
                unsigned m = ((cya[i] + (unsigned)(pi & 1)) * P1) ^
                             ((cza[i] + (unsigned)(pi >> 1)) * P2);
                unsigned h0 = (cxa[i] ^ m) & mask;
                bool hi = (h0 & 1u) != 0u;
                unsigned e0b = hi ? pr[i][pi].y : pr[i][pi].x;
                unsigned e1b;
                if (odd) {
                    unsigned h1 = ((cxa[i] + 1u) ^ m) & mask;
                    e1b = lvl32[h1];
                } else {
                    e1b = hi ? pr[i][pi].x : pr[i][pi].y;
                }
                float wy = (pi & 1) ? fy : gy;
                float wz = (pi >> 1) ? fz : gz;
                float wyz = wy * wz;
                f16x2 e0 = __builtin_bit_cast(f16x2, e0b);
                f16x2 e1 = __builtin_bit_cast(f16x2, e1b);
                float w0 = gx * wyz;
                float w1 = fx * wyz;
                o0 += w0 * (float)e0.x;  o1 += w0 * (float)e0.y;
                o0 += w1 * (float)e1.x;  o1 += w1 * (float)e1.y;
            }
            o0a[i] = o0; o1a[i] = o1;
        }
    } else {
        const f32x2* lvl = reinterpret_cast<const f32x2*>(emb) + off;
#pragma unroll
        for (int i = 0; i < PPT; ++i) {
            float fx = fxa[i], fy = fya[i], fz = fza[i];
            float gx = qxa[i], gy = qya[i], gz = qza[i];
            float o0 = 0.0f, o1 = 0.0f;
#pragma unroll
            for (int c = 0; c < 8; ++c) {
                unsigned bx = (unsigned)(c & 1);
                unsigned by = (unsigned)((c >> 1) & 1);
                unsigned bz = (unsigned)((c >> 2) & 1);
                unsigned h = hash3(cxa[i] + bx, cya[i] + by, cza[i] + bz);
                unsigned hm = pow2 ? (h & mask) : (h % size);
                f32x2 e = lvl[hm];
                float w = (bx ? fx : gx) * (by ? fy : gy);
                w = w * (bz ? fz : gz);
                o0 += w * e.x;
                o1 += w * e.y;
            }
            o0a[i] = o0; o1a[i] = o1;
        }
    }

#pragma unroll
    for (int i = 0; i < PPT; ++i) {
        if (!valid[i]) { o0a[i] = 0.0f; o1a[i] = 0.0f; }
    }

    if (use_scratch) {
        unsigned hb0, hb1, hb2, hb3;
        {
            f16x2 h; h.x = (_Float16)o0a[0]; h.y = (_Float16)o1a[0];
            hb0 = __builtin_bit_cast(unsigned, h);
        }
        {
            f16x2 h; h.x = (_Float16)o0a[1]; h.y = (_Float16)o1a[1];
            hb1 = __builtin_bit_cast(unsigned, h);
        }
        {
            f16x2 h; h.x = (_Float16)o0a[2]; h.y = (_Float16)o1a[2];
            hb2 = __builtin_bit_cast(unsigned, h);
        }
        {
            f16x2 h; h.x = (_Float16)o0a[3]; h.y = (_Float16)o1a[3];
            hb3 = __builtin_bit_cast(unsigned, h);
        }
        if (p0 + PPT <= B) {
            u32x4 sv; sv.x = hb0; sv.y = hb1; sv.z = hb2; sv.w = hb3;
            u32x4* op = reinterpret_cast<u32x4*>(
                reinterpret_cast<unsigned*>(scratch) + (size_t)l * B + p0);
            __builtin_nontemporal_store(sv, op);
        } else {
            unsigned hbs[PPT] = {hb0, hb1, hb2, hb3};
#pragma unroll
            for (int i = 0; i < PPT; ++i) {
                int p = p0 + i;
                if (p < B) {
                    unsigned* op = reinterpret_cast<unsigned*>(scratch) + (size_t)l * B + p;
                    __builtin_nontemporal_store(hbs[i], op);
                }
            }
        }
    } else {
#pragma unroll
        for (int i = 0; i < PPT; ++i) {
            int p = p0 + i;
            if (p < B) {
                f32x2 r; r.x = o0a[i]; r.y = o1a[i];
                f32x2* op = reinterpret_cast<f32x2*>(out + (size_t)p * (NLVL * 2) + l * 2);
                __builtin_nontemporal_store(r, op);
            }
        }
    }
}

// ---- transpose scratch(fp16)[l][p] -> out(f32)[p][l] via LDS tile ----
__global__ __launch_bounds__(256) void transpose_kernel(
    const float* __restrict__ scratch,
    float*       __restrict__ out,
    int B)
{
    __shared__ float tile[64][33];
    const int p0 = blockIdx.x * 64;
    const int tid = (int)threadIdx.x;

    const unsigned* src = reinterpret_cast<const unsigned*>(scratch);
#pragma unroll
    for (int k = 0; k < 4; ++k) {
        int it = tid + k * 256;
        int l  = it >> 6;
        int pi = it & 63;
        int p  = p0 + pi;
        unsigned vb = (p < B) ? src[(size_t)l * B + p] : 0u;
        f16x2 v = __builtin_bit_cast(f16x2, vb);
        tile[pi][2 * l]     = (float)v.x;
        tile[pi][2 * l + 1] = (float)v.y;
    }
    __syncthreads();

    const int pl = tid >> 2;
    const int q  = tid & 3;
    const int p  = p0 + pl;
    if (p >= B) return;
    float vals[8];
#pragma unroll
    for (int j = 0; j < 8; ++j) vals[j] = tile[pl][q * 8 + j];
    f32x4 lo, hi;
    lo.x = vals[0]; lo.y = vals[1]; lo.z = vals[2]; lo.w = vals[3];
    hi.x = vals[4]; hi.y = vals[5]; hi.z = vals[6]; hi.w = vals[7];
    f32x4* dst = reinterpret_cast<f32x4*>(out + (size_t)p * 32 + q * 8);
    __builtin_nontemporal_store(lo, dst);
    __builtin_nontemporal_store(hi, dst + 1);
}

extern "C" void kernel_launch(void* const* d_in, const int* in_sizes, int n_in,
                              void* d_out, int out_size, void* d_ws, size_t ws_size,
                              hipStream_t stream) {
    const float* xyz        = (const float*)d_in[0];
    const float* embeddings = (const float*)d_in[1];
    const int*   offsets    = (const int*)d_in[2];
    const int*   resolutions= (const int*)d_in[3];
    const float* min_xyz    = (const float*)d_in[4];
    const float* max_xyz    = (const float*)d_in[5];
    float* out = (float*)d_out;

    int B = in_sizes[0] / 3;
    int n_entries = in_sizes[1] / 2;                       // total table entries (F=2)

    size_t scratch_bytes = (size_t)B * NLVL * 4;           // f16x2 per (l,p)
    size_t htab_bytes    = (size_t)n_entries * 4;          // f16x2 per entry
    size_t bdense_bytes  = (size_t)BDENSE_CAP * 16;        // 16B quads

    int use_scratch = (ws_size >= scratch_bytes) ? 1 : 0;
    size_t htab_off = use_scratch ? scratch_bytes : 0;
    int use_fp16 = (ws_size >= htab_off + htab_bytes) ? 1 : 0;
    size_t bdense_off = htab_off + (use_fp16 ? htab_bytes : 0);
    int use_bdense = (use_fp16 && ws_size >= bdense_off + bdense_bytes) ? 1 : 0;

    float*    scratch = (float*)d_ws;
    _Float16* htab    = (_Float16*)((char*)d_ws + htab_off);
    unsigned* bdense  = (unsigned*)((char*)d_ws + bdense_off);

    if (use_fp16) {
        int cgrid = (n_entries + 255) / 256;
        convert_fp16_kernel<<<cgrid, 256, 0, stream>>>(embeddings, htab, n_entries);
    }
    if (use_bdense) {
        int pgrid = (BDENSE_CAP + 255) / 256;
        bdensify_kernel<<<pgrid, 256, 0, stream>>>(
            (const unsigned*)htab, offsets, resolutions, bdense);
    }
    int nchunks = (B + (256 * PPT) - 1) / (256 * PPT);
    int grid = nchunks * NLVL;
    encode_kernel<<<grid, 256, 0, stream>>>(
        xyz, embeddings, htab, offsets, resolutions, min_xyz, max_xyz,
        bdense, scratch, out, B, use_bdense, use_scratch, use_fp16);
    if (use_scratch) {
        int tgrid = (B + 63) / 64;
        transpose_kernel<<<tgrid, 256, 0, stream>>>(scratch, out, B);
    }
}